// Round 4
// baseline (354.973 us; speedup 1.0000x reference)
//
#include <hip/hip_runtime.h>
#include <math.h>

#define BB 64
#define NN 1024
#define HID 64
#define STATE 32
#define NTYPES 10
#define CAP 256           // per-bucket row capacity (c ~ Binom(1024,0.1), 16-sigma safe)
#define CAPE (CAP * 64)   // f16 elems per packed bucket matrix

typedef _Float16 f16;
typedef f16 f16x8 __attribute__((ext_vector_type(8)));
typedef f16 f16x4 __attribute__((ext_vector_type(4)));
typedef float f32x4 __attribute__((ext_vector_type(4)));

#define MFMA16(a, b, c) __builtin_amdgcn_mfma_f32_16x16x32_f16(a, b, c, 0, 0, 0)

__device__ __forceinline__ float sigm(float x) { return 1.f / (1.f + expf(-x)); }

__device__ __forceinline__ f16x8 cvt8(float4 a, float4 b) {
    f16x8 r;
    r[0] = (f16)a.x; r[1] = (f16)a.y; r[2] = (f16)a.z; r[3] = (f16)a.w;
    r[4] = (f16)b.x; r[5] = (f16)b.y; r[6] = (f16)b.z; r[7] = (f16)b.w;
    return r;
}
__device__ __forceinline__ unsigned packh2(f16 a, f16 b) {
    union { f16 h[2]; unsigned u; } p;
    p.h[0] = a; p.h[1] = b;
    return p.u;
}

// swizzle n f32 weights (o-major, K inner) into MFMA B-frag f16 layout in LDS
__device__ __forceinline__ void swz_load(const float* __restrict__ W, int K, int n,
                                         f16* dst, int tid) {
    for (int p = tid; p < n; p += 256) {
        int j = p & 7, ln = (p >> 3) & 63, nt = (p >> 9) & 3, ch = p >> 11;
        int k = ch * 32 + ((ln >> 4) << 3) + j;
        int o = nt * 16 + (ln & 15);
        dst[p] = (f16)W[o * K + k];
    }
}

// release: call AFTER __syncthreads() (barrier drains vmcnt -> stores in L2).
// tid0's threadfence writes back the XCD L2; atomicAdd is device-scope (sc1).
__device__ __forceinline__ void bar_signal(int* bar, int tid) {
    if (tid == 0) { __threadfence(); atomicAdd(bar, 1); }
}
// acquire: spin on device-scope acquire load (invalidates CU L1 + XCD L2),
// then block barrier so every thread's subsequent loads see fresh data.
__device__ __forceinline__ void bar_wait(int* bar, int target, int tid) {
    if (tid == 0) {
        while (__hip_atomic_load(bar, __ATOMIC_ACQUIRE, __HIP_MEMORY_SCOPE_AGENT) < target)
            __builtin_amdgcn_s_sleep(2);
    }
    __syncthreads();
}

#define TSTR2 72

// =====================================================================
// K1: encoder (2 tiles/block) -> barE(16) -> buildM0(b,t) -> bar0(10)
//     -> gnn0 + fused M1 build.  640 blocks, 256 threads, 34816 B LDS.
// =====================================================================
__global__ __launch_bounds__(256, 3) void k_front(
    const float* __restrict__ feat,
    const float* __restrict__ w1, const float* __restrict__ b1,
    const float* __restrict__ w2, const float* __restrict__ b2,
    const int* __restrict__ types, int* __restrict__ idx, int* __restrict__ cnt,
    f16* __restrict__ nrmp, float* __restrict__ sclp, float* __restrict__ ctx,
    const float* __restrict__ cont, const float* __restrict__ gw0,
    const float* __restrict__ gb0,
    f16* __restrict__ M0, f16* __restrict__ M1, f16* __restrict__ h1p,
    int* __restrict__ barE, int* __restrict__ bar0)
{
    __shared__ __align__(16) unsigned char smem[34816];
    // phase E layout: w2s [0,8192) tmp [8192,17408) fbuf [17408,18176) pkbuf [18176,18432)
    // phase M/gnn0:   nT [0,9216) hT [9216,18432)
    // persistent:     gs [18432,26624) ds_ [26624,34816)
    f16* w2s = (f16*)smem;
    f16* tmp = (f16*)(smem + 8192);
    float* fb = (float*)(smem + 17408);
    int* pkbuf = (int*)(smem + 18176);
    f16* nT = (f16*)smem;
    f16* hT = (f16*)(smem + 9216);
    f16* gs = (f16*)(smem + 18432);
    f16* ds_ = (f16*)(smem + 26624);

    const int tid = threadIdx.x, wave = tid >> 6, lane = tid & 63;
    const int l15 = lane & 15, quad = lane >> 4;
    const int bid = blockIdx.x;

    // role (b,t): siblings of a batch share an XCD (bid&7)
    const int xcd = bid & 7, kk = bid >> 3;
    const int rb = xcd + 8 * (kk / NTYPES);
    const int rt = kk % NTYPES;
    const int rbt = rb * NTYPES + rt;

    // ---- persistent loads (regions untouched by encoder phase)
    swz_load(gw0, 64, 4096, gs, tid);
    if (bid < 16) ctx[bid * 256 + tid] = 0.f;

    // ---- phase E: encoder, tiles bid and bid+640
    swz_load(w2, 64, 4096, w2s, tid);
    float w10 = w1[lane * 3], w11 = w1[lane * 3 + 1], w12 = w1[lane * 3 + 2], b1l = b1[lane];
    float b2c[4];
#pragma unroll
    for (int nt = 0; nt < 4; ++nt) b2c[nt] = b2[nt * 16 + l15];
    f16* tw = &tmp[wave * (16 * 72)];
    float* fw = &fb[wave * 48];
    const f16x8* wbf = (const f16x8*)w2s;
    for (int tile = bid; tile < BB * NN / 64; tile += 640) {
        int tbatch = tile >> 4;
        if (tid < 64) {
            int row = tile * 64 + tid;
            int t = types[row];
            int bt = tbatch * NTYPES + t;
            int pos = atomicAdd(&cnt[bt], 1);
            idx[bt * CAP + pos] = row & (NN - 1);
            pkbuf[tid] = bt * CAP + pos;
        }
        int tb = tile * 64 + wave * 16;
        if (lane < 48) fw[lane] = feat[tb * 3 + lane];
        __syncthreads();   // pkbuf/fbuf ready (and protects smem reuse per iter)
#pragma unroll
        for (int r = 0; r < 16; ++r) {
            float x0 = fw[r * 3], x1 = fw[r * 3 + 1], x2 = fw[r * 3 + 2];
            float hv = fmaxf(fmaf(w10, x0, fmaf(w11, x1, fmaf(w12, x2, b1l))), 0.f);
            tw[r * 72 + lane] = (f16)hv;
        }
        __builtin_amdgcn_sched_barrier(0);   // tmp is wave-local
        f16x8 a0 = *(const f16x8*)&tw[l15 * 72 + quad * 8];
        f16x8 a1 = *(const f16x8*)&tw[l15 * 72 + 32 + quad * 8];
        f32x4 acc[4];
#pragma unroll
        for (int nt = 0; nt < 4; ++nt) {
            f32x4 c = {0.f, 0.f, 0.f, 0.f};
            c = MFMA16(a0, wbf[(0 * 4 + nt) * 64 + lane], c);
            c = MFMA16(a1, wbf[(1 * 4 + nt) * 64 + lane], c);
            acc[nt] = c;
        }
#pragma unroll
        for (int i = 0; i < 4; ++i) {
            float v[4]; float ss = 0.f;
#pragma unroll
            for (int nt = 0; nt < 4; ++nt) { v[nt] = acc[nt][i] + b2c[nt]; ss = fmaf(v[nt], v[nt], ss); }
            ss += __shfl_xor(ss, 1, 64); ss += __shfl_xor(ss, 2, 64);
            ss += __shfl_xor(ss, 4, 64); ss += __shfl_xor(ss, 8, 64);
            float nm = fmaxf(sqrtf(ss), 1e-12f);
            float rinv = 1.f / nm;
            int pk = pkbuf[wave * 16 + quad * 4 + i];
#pragma unroll
            for (int nt = 0; nt < 4; ++nt)
                nrmp[(size_t)pk * 64 + nt * 16 + l15] = (f16)(v[nt] * rinv);
            if (l15 == 0) sclp[pk] = nm;
        }
        __syncthreads();   // all stores issued+drained (vmcnt0 at barrier)
        bar_signal(&barE[tbatch], tid);
    }

    // ---- wait: all 16 tiles of role batch encoded
    bar_wait(&barE[rb], 16, tid);
    int c = cnt[rbt];

    // ---- phase M0: M0_bt = nrm^T @ (scl*nrm), packed sequential
    {
        int r = tid & 15, q4 = tid >> 4;
        const f16* nb = nrmp + (size_t)rbt * CAPE;
        const float* sb = sclp + (size_t)rbt * CAP;
        f32x4 acc[4] = {{0.f,0.f,0.f,0.f},{0.f,0.f,0.f,0.f},{0.f,0.f,0.f,0.f},{0.f,0.f,0.f,0.f}};
        for (int k0 = 0; k0 < c; k0 += 64) {
            __syncthreads();
            f16x4 a[4], g[4];
#pragma unroll
            for (int u = 0; u < 4; ++u) { a[u] = (f16x4){0,0,0,0}; g[u] = (f16x4){0,0,0,0}; }
#pragma unroll
            for (int u = 0; u < 4; ++u) {
                int mi = k0 + 4 * r + u;
                if (mi < c) {
                    a[u] = *(const f16x4*)&nb[(size_t)mi * 64 + 4 * q4];
                    f16 sm = (f16)sb[mi]; f16x4 sv = {sm, sm, sm, sm};
                    g[u] = a[u] * sv;
                }
            }
#pragma unroll
            for (int i = 0; i < 4; ++i) {
                *(unsigned*)&nT[(4 * q4 + i) * TSTR2 + 4 * r]     = packh2(a[0][i], a[1][i]);
                *(unsigned*)&nT[(4 * q4 + i) * TSTR2 + 4 * r + 2] = packh2(a[2][i], a[3][i]);
                *(unsigned*)&hT[(4 * q4 + i) * TSTR2 + 4 * r]     = packh2(g[0][i], g[1][i]);
                *(unsigned*)&hT[(4 * q4 + i) * TSTR2 + 4 * r + 2] = packh2(g[2][i], g[3][i]);
            }
            __syncthreads();
            f16x8 af0 = *(const f16x8*)&nT[(wave * 16 + l15) * TSTR2 + quad * 8];
            f16x8 af1 = *(const f16x8*)&nT[(wave * 16 + l15) * TSTR2 + 32 + quad * 8];
#pragma unroll
            for (int nt = 0; nt < 4; ++nt) {
                f16x8 bf0 = *(const f16x8*)&hT[(nt * 16 + l15) * TSTR2 + quad * 8];
                f16x8 bf1 = *(const f16x8*)&hT[(nt * 16 + l15) * TSTR2 + 32 + quad * 8];
                acc[nt] = MFMA16(af0, bf0, acc[nt]);
                acc[nt] = MFMA16(af1, bf1, acc[nt]);
            }
        }
        f16* Mo = M0 + (size_t)rbt * 4096;
#pragma unroll
        for (int nt = 0; nt < 4; ++nt)
#pragma unroll
            for (int i = 0; i < 4; ++i)
                Mo[(wave * 16 + quad * 4 + i) * 64 + nt * 16 + l15] = (f16)acc[nt][i];
    }
    __syncthreads();
    bar_signal(&bar0[rb], tid);
    bar_wait(&bar0[rb], 10, tid);

    // ---- phase gnn0 + fused M1 build
    {
        float sg[NTYPES];
#pragma unroll
        for (int j = 0; j < NTYPES; ++j) sg[j] = sigm(cont[rt * NTYPES + j]);
        float ca[16];
#pragma unroll
        for (int i = 0; i < 16; ++i) ca[i] = 0.f;
        const f16* Mb = M0 + (size_t)rb * NTYPES * 4096;
#pragma unroll
        for (int j = 0; j < NTYPES; ++j) {
            const f16* Mr = Mb + j * 4096 + (wave * 16 + l15) * 64;
            f16x8 m0 = *(const f16x8*)&Mr[quad * 8];
            f16x8 m1 = *(const f16x8*)&Mr[32 + quad * 8];
            float sv = sg[j];
#pragma unroll
            for (int e = 0; e < 8; ++e) {
                ca[e]     = fmaf(sv, (float)m0[e], ca[e]);
                ca[8 + e] = fmaf(sv, (float)m1[e], ca[8 + e]);
            }
        }
        f16x8 ca0, ca1;
#pragma unroll
        for (int i = 0; i < 8; ++i) { ca0[i] = (f16)ca[i]; ca1[i] = (f16)ca[8 + i]; }
        const f16x8* gbf = (const f16x8*)gs;
#pragma unroll
        for (int nt = 0; nt < 4; ++nt) {
            f32x4 dd = {0.f, 0.f, 0.f, 0.f};
            dd = MFMA16(ca0, gbf[(0 * 4 + nt) * 64 + lane], dd);
            dd = MFMA16(ca1, gbf[(1 * 4 + nt) * 64 + lane], dd);
#pragma unroll
            for (int i = 0; i < 4; ++i) {
                int d = wave * 16 + quad * 4 + i;
                int pos = (((d >> 5) * 4 + nt) * 64 + ((d >> 3) & 3) * 16 + l15) * 8 + (d & 7);
                ds_[pos] = (f16)dd[i];
            }
        }
        __syncthreads();   // D ready
        float gbl[4];
#pragma unroll
        for (int nt = 0; nt < 4; ++nt) gbl[nt] = gb0[nt * 16 + l15];
        const f16* nb = nrmp + (size_t)rbt * CAPE;
        const float* sb = sclp + (size_t)rbt * CAP;
        f16* hob = h1p + (size_t)rbt * CAPE;
        const f16x8* dbf = (const f16x8*)ds_;
        f32x4 macc[4];
#pragma unroll
        for (int nt = 0; nt < 4; ++nt) macc[nt] = (f32x4){0.f, 0.f, 0.f, 0.f};
        int nchunk = (c + 63) >> 6;
        for (int ch = 0; ch < nchunk; ++ch) {
            int tb = ch * 64 + wave * 16;
            int rA = tb + l15;
            bool okA = rA < c;
            int rAc = okA ? rA : (c - 1);
            const f16* na = nb + (size_t)rAc * 64;
            f16x8 a0 = *(const f16x8*)&na[quad * 8];
            f16x8 a1 = *(const f16x8*)&na[32 + quad * 8];
            f32x4 acc1[4], acc2[4];
#pragma unroll
            for (int nt = 0; nt < 4; ++nt) {
                f32x4 c1 = {0.f, 0.f, 0.f, 0.f}, c2 = {0.f, 0.f, 0.f, 0.f};
                c1 = MFMA16(a0, dbf[(0 * 4 + nt) * 64 + lane], c1);
                c1 = MFMA16(a1, dbf[(1 * 4 + nt) * 64 + lane], c1);
                c2 = MFMA16(a0, gbf[(0 * 4 + nt) * 64 + lane], c2);
                c2 = MFMA16(a1, gbf[(1 * 4 + nt) * 64 + lane], c2);
                acc1[nt] = c1; acc2[nt] = c2;
            }
            f16x4 hv[4];
#pragma unroll
            for (int nt = 0; nt < 4; ++nt) hv[nt] = (f16x4){0, 0, 0, 0};
#pragma unroll
            for (int i = 0; i < 4; ++i) {
                int rr = tb + quad * 4 + i;
                if (rr < c) {
                    float sm = sb[rr];
#pragma unroll
                    for (int nt = 0; nt < 4; ++nt) {
                        float v = fmaxf(fmaf(sm, acc2[nt][i], acc1[nt][i]) + gbl[nt], 0.f);
                        f16 vh = (f16)v;
                        hob[(size_t)rr * 64 + nt * 16 + l15] = vh;
                        hv[nt][i] = vh;
                    }
                }
            }
            f16x8 z8 = {0, 0, 0, 0, 0, 0, 0, 0};
            f16x8 s0 = okA ? a0 : z8;
            f16x8 s1 = okA ? a1 : z8;
#pragma unroll
            for (int j = 0; j < 8; ++j) {
                nT[(quad * 8 + j) * TSTR2 + wave * 16 + l15]      = s0[j];
                nT[(32 + quad * 8 + j) * TSTR2 + wave * 16 + l15] = s1[j];
            }
#pragma unroll
            for (int nt = 0; nt < 4; ++nt)
                *(f16x4*)&hT[(nt * 16 + l15) * TSTR2 + wave * 16 + quad * 4] = hv[nt];
            __syncthreads();
            f16x8 af0 = *(const f16x8*)&nT[(wave * 16 + l15) * TSTR2 + quad * 8];
            f16x8 af1 = *(const f16x8*)&nT[(wave * 16 + l15) * TSTR2 + 32 + quad * 8];
#pragma unroll
            for (int nt = 0; nt < 4; ++nt) {
                f16x8 bf0 = *(const f16x8*)&hT[(nt * 16 + l15) * TSTR2 + quad * 8];
                f16x8 bf1 = *(const f16x8*)&hT[(nt * 16 + l15) * TSTR2 + 32 + quad * 8];
                macc[nt] = MFMA16(af0, bf0, macc[nt]);
                macc[nt] = MFMA16(af1, bf1, macc[nt]);
            }
            __syncthreads();
        }
        f16* Mo = M1 + (size_t)rbt * 4096;
#pragma unroll
        for (int nt = 0; nt < 4; ++nt)
#pragma unroll
            for (int i = 0; i < 4; ++i)
                Mo[(wave * 16 + quad * 4 + i) * 64 + nt * 16 + l15] = (f16)macc[nt][i];
    }
}

// =====================================================================
// K2: gnn1 (+ctx) -> bar1(10) -> GRU + head.  640 blocks, ~30 KB LDS.
// =====================================================================
__global__ __launch_bounds__(256, 3) void k_back(
    const int* __restrict__ cnt, const float* __restrict__ cont,
    const f16* __restrict__ M1, const f16* __restrict__ nrmp,
    const f16* __restrict__ h1p,
    const float* __restrict__ gw1, const float* __restrict__ gb1,
    f16* __restrict__ h2p, float* __restrict__ ctx,
    const int* __restrict__ idx, const float* __restrict__ prev,
    const float* __restrict__ w_ih, const float* __restrict__ w_hh,
    const float* __restrict__ b_ih, const float* __restrict__ b_hh,
    const float* __restrict__ hw1, const float* __restrict__ hb1,
    const float* __restrict__ hw2, const float* __restrict__ hb2,
    float* __restrict__ lat, float* __restrict__ state_out,
    int* __restrict__ bar1)
{
    __shared__ f16 ds_[4096];
    __shared__ f16 gs[4096];
    __shared__ f16 ws_[6144];
    __shared__ __align__(16) float st[STATE];
    __shared__ float cs[HID], ps[STATE], gis[96], ghs[96];
    const int tid = threadIdx.x, wave = tid >> 6, lane = tid & 63;
    const int l15 = lane & 15, quad = lane >> 4;
    const int bid = blockIdx.x;
    const int xcd = bid & 7, kk = bid >> 3;
    const int b = xcd + 8 * (kk / NTYPES);
    const int t = kk % NTYPES;
    const int bt = b * NTYPES + t;
    const int c = cnt[bt];

    swz_load(gw1, 64, 4096, gs, tid);
    swz_load(hw1, 96, 6144, ws_, tid);
    if (tid >= HID && tid < HID + STATE) ps[tid - HID] = prev[b * STATE + tid - HID];
    __syncthreads();

    if (c > 0) {
        float sg[NTYPES];
#pragma unroll
        for (int j = 0; j < NTYPES; ++j) sg[j] = sigm(cont[t * NTYPES + j]);
        float ca[16];
#pragma unroll
        for (int i = 0; i < 16; ++i) ca[i] = 0.f;
        const f16* Mb = M1 + (size_t)b * NTYPES * 4096;
#pragma unroll
        for (int j = 0; j < NTYPES; ++j) {
            const f16* Mr = Mb + j * 4096 + (wave * 16 + l15) * 64;
            f16x8 m0 = *(const f16x8*)&Mr[quad * 8];
            f16x8 m1 = *(const f16x8*)&Mr[32 + quad * 8];
            float sv = sg[j];
#pragma unroll
            for (int e = 0; e < 8; ++e) {
                ca[e]     = fmaf(sv, (float)m0[e], ca[e]);
                ca[8 + e] = fmaf(sv, (float)m1[e], ca[8 + e]);
            }
        }
        f16x8 ca0, ca1;
#pragma unroll
        for (int i = 0; i < 8; ++i) { ca0[i] = (f16)ca[i]; ca1[i] = (f16)ca[8 + i]; }
        const f16x8* gbf = (const f16x8*)gs;
#pragma unroll
        for (int nt = 0; nt < 4; ++nt) {
            f32x4 dd = {0.f, 0.f, 0.f, 0.f};
            dd = MFMA16(ca0, gbf[(0 * 4 + nt) * 64 + lane], dd);
            dd = MFMA16(ca1, gbf[(1 * 4 + nt) * 64 + lane], dd);
#pragma unroll
            for (int i = 0; i < 4; ++i) {
                int d = wave * 16 + quad * 4 + i;
                int pos = (((d >> 5) * 4 + nt) * 64 + ((d >> 3) & 3) * 16 + l15) * 8 + (d & 7);
                ds_[pos] = (f16)dd[i];
            }
        }
        __syncthreads();   // D ready
        float gbl[4];
#pragma unroll
        for (int nt = 0; nt < 4; ++nt) gbl[nt] = gb1[nt * 16 + l15];
        const f16* nb = nrmp + (size_t)bt * CAPE;
        const f16* hb = h1p + (size_t)bt * CAPE;
        f16* hob = h2p + (size_t)bt * CAPE;
        const f16x8* dbf = (const f16x8*)ds_;
        float cacc[4] = {0.f, 0.f, 0.f, 0.f};
        for (int g = wave; g * 16 < c; g += 4) {
            int tb = g * 16;
            int rA = tb + l15; if (rA >= c) rA = c - 1;
            const f16* na = nb + (size_t)rA * 64;
            f16x8 a0 = *(const f16x8*)&na[quad * 8];
            f16x8 a1 = *(const f16x8*)&na[32 + quad * 8];
            const f16* ha = hb + (size_t)rA * 64;
            f16x8 h0 = *(const f16x8*)&ha[quad * 8];
            f16x8 h1 = *(const f16x8*)&ha[32 + quad * 8];
            f32x4 acc[4];
#pragma unroll
            for (int nt = 0; nt < 4; ++nt) {
                f32x4 cc = {0.f, 0.f, 0.f, 0.f};
                cc = MFMA16(a0, dbf[(0 * 4 + nt) * 64 + lane], cc);
                cc = MFMA16(a1, dbf[(1 * 4 + nt) * 64 + lane], cc);
                cc = MFMA16(h0, gbf[(0 * 4 + nt) * 64 + lane], cc);
                cc = MFMA16(h1, gbf[(1 * 4 + nt) * 64 + lane], cc);
                acc[nt] = cc;
            }
#pragma unroll
            for (int i = 0; i < 4; ++i) {
                int rr = tb + quad * 4 + i;
                if (rr < c) {
#pragma unroll
                    for (int nt = 0; nt < 4; ++nt) {
                        float v = fmaxf(acc[nt][i] + gbl[nt], 0.f);
                        hob[(size_t)rr * 64 + nt * 16 + l15] = (f16)v;
                        cacc[nt] += v;
                    }
                }
            }
        }
#pragma unroll
        for (int nt = 0; nt < 4; ++nt) {
            float sv = cacc[nt];
            sv += __shfl_xor(sv, 16, 64);
            sv += __shfl_xor(sv, 32, 64);
            if (quad == 0) atomicAdd(&ctx[b * HID + nt * 16 + l15], sv);
        }
    }
    __syncthreads();
    bar_signal(&bar1[b], tid);
    bar_wait(&bar1[b], 10, tid);

    // ---- head: GRU (redundant per block) + own bucket rows
    if (tid < HID) cs[tid] = ctx[b * HID + tid] * (1.f / NN);
    __syncthreads();
    if (tid < 96) {
        float gi = b_ih[tid];
#pragma unroll 8
        for (int k = 0; k < HID; ++k) gi = fmaf(w_ih[tid * HID + k], cs[k], gi);
        float gh = b_hh[tid];
#pragma unroll
        for (int k = 0; k < STATE; ++k) gh = fmaf(w_hh[tid * STATE + k], ps[k], gh);
        gis[tid] = gi; ghs[tid] = gh;
    }
    __syncthreads();
    if (tid < STATE) {
        float r = sigm(gis[tid] + ghs[tid]);
        float z = sigm(gis[32 + tid] + ghs[32 + tid]);
        float nn = tanhf(gis[64 + tid] + r * ghs[64 + tid]);
        float v = (1.f - z) * nn + z * ps[tid];
        st[tid] = v;
        if (t == 0) state_out[b * STATE + tid] = v;
    }
    __syncthreads();
    if (c == 0) return;
    float b1c[4], w2c[4];
#pragma unroll
    for (int nt = 0; nt < 4; ++nt) { b1c[nt] = hb1[nt * 16 + l15]; w2c[nt] = hw2[nt * 16 + l15]; }
    float b2v = hb2[0];
    const float4* sp = (const float4*)st;
    f16x8 a2 = cvt8(sp[quad * 2], sp[quad * 2 + 1]);
    const f16x8* bf = (const f16x8*)ws_;
    const f16* hb = h2p + (size_t)bt * CAPE;
    const int* lst = idx + (size_t)bt * CAP;
    for (int g = wave; g * 16 < c; g += 4) {
        int tb = g * 16;
        int rA = tb + l15; if (rA >= c) rA = c - 1;
        const f16* ha = hb + (size_t)rA * 64;
        f16x8 a0 = *(const f16x8*)&ha[quad * 8];
        f16x8 a1 = *(const f16x8*)&ha[32 + quad * 8];
        f32x4 acc[4];
#pragma unroll
        for (int nt = 0; nt < 4; ++nt) {
            f32x4 cc = {0.f, 0.f, 0.f, 0.f};
            cc = MFMA16(a0, bf[(0 * 4 + nt) * 64 + lane], cc);
            cc = MFMA16(a1, bf[(1 * 4 + nt) * 64 + lane], cc);
            cc = MFMA16(a2, bf[(2 * 4 + nt) * 64 + lane], cc);
            acc[nt] = cc;
        }
#pragma unroll
        for (int i = 0; i < 4; ++i) {
            float s = 0.f;
#pragma unroll
            for (int nt = 0; nt < 4; ++nt) s = fmaf(fmaxf(acc[nt][i] + b1c[nt], 0.f), w2c[nt], s);
            s += __shfl_xor(s, 1, 64); s += __shfl_xor(s, 2, 64);
            s += __shfl_xor(s, 4, 64); s += __shfl_xor(s, 8, 64);
            int rr = tb + quad * 4 + i;
            if (l15 == 0 && rr < c) {
                int m = lst[rr];
                lat[b * NN + m] = s + b2v;
            }
        }
    }
}

extern "C" void kernel_launch(void* const* d_in, const int* in_sizes, int n_in,
                              void* d_out, int out_size, void* d_ws, size_t ws_size,
                              hipStream_t stream) {
    const float* feat   = (const float*)d_in[0];
    const int*   types  = (const int*)d_in[1];
    const float* prev   = (const float*)d_in[2];
    const float* enc_w1 = (const float*)d_in[3];
    const float* enc_b1 = (const float*)d_in[4];
    const float* enc_w2 = (const float*)d_in[5];
    const float* enc_b2 = (const float*)d_in[6];
    const float* cont   = (const float*)d_in[7];
    const float* gnn_w  = (const float*)d_in[8];
    const float* gnn_b  = (const float*)d_in[9];
    const float* w_ih   = (const float*)d_in[10];
    const float* w_hh   = (const float*)d_in[11];
    const float* b_ih   = (const float*)d_in[12];
    const float* b_hh   = (const float*)d_in[13];
    const float* hw1    = (const float*)d_in[14];
    const float* hb1    = (const float*)d_in[15];
    const float* hw2    = (const float*)d_in[16];
    const float* hb2    = (const float*)d_in[17];
    float* out = (float*)d_out;

    float* ws   = (float*)d_ws;
    f16*   nrmp = (f16*)ws;                    // 10485760 f16 (640*CAP*64)
    f16*   h1p  = (f16*)(ws + 5242880);        // 10485760 f16
    f16*   h2p  = (f16*)(ws + 10485760);       // 10485760 f16
    float* sclp = ws + 15728640;               // 163840 f32
    int*   idx  = (int*)(ws + 15892480);       // 163840 i32
    int*   cnt  = (int*)(ws + 16056320);       // 640 i32
    int*   barE = cnt + 640;                   // 64
    int*   bar0 = barE + 64;                   // 64
    int*   bar1 = bar0 + 64;                   // 64  (total 832 ints < 1024 pad)
    f16*   M0   = (f16*)(ws + 16057344);       // 2621440 f16
    f16*   M1   = (f16*)(ws + 17368064);       // 2621440 f16
    float* ctx  = ws + 18678784;               // 4096 f32

    hipMemsetAsync(cnt, 0, 832 * sizeof(int), stream);
    k_front<<<BB * NTYPES, 256, 0, stream>>>(feat, enc_w1, enc_b1, enc_w2, enc_b2,
                                             types, idx, cnt, nrmp, sclp, ctx,
                                             cont, gnn_w, gnn_b, M0, M1, h1p,
                                             barE, bar0);
    k_back<<<BB * NTYPES, 256, 0, stream>>>(cnt, cont, M1, nrmp, h1p,
                                            gnn_w + 4096, gnn_b + HID, h2p, ctx,
                                            idx, prev, w_ih, w_hh, b_ih, b_hh,
                                            hw1, hb1, hw2, hb2,
                                            out, out + BB * NN, bar1);
}

// Round 5
// 317.497 us; speedup vs baseline: 1.1180x; 1.1180x over previous
//
#include <hip/hip_runtime.h>
#include <math.h>

#define BB 64
#define NN 1024
#define HID 64
#define STATE 32
#define NTYPES 10
#define CAP 256           // per-bucket capacity (c ~ Binom(1024,0.1); 16-sigma safe)
#define CAPE (CAP * 64)
#define TSTR3 40          // 32 k-slots + 8 pad; 80B row stride keeps b128 16B-aligned

typedef _Float16 f16;
typedef f16 f16x8 __attribute__((ext_vector_type(8)));
typedef f16 f16x4 __attribute__((ext_vector_type(4)));
typedef float f32x4 __attribute__((ext_vector_type(4)));

#define MFMA16(a, b, c) __builtin_amdgcn_mfma_f32_16x16x32_f16(a, b, c, 0, 0, 0)

__device__ __forceinline__ float sigm(float x) { return 1.f / (1.f + expf(-x)); }

__device__ __forceinline__ f16x8 cvt8(float4 a, float4 b) {
    f16x8 r;
    r[0] = (f16)a.x; r[1] = (f16)a.y; r[2] = (f16)a.z; r[3] = (f16)a.w;
    r[4] = (f16)b.x; r[5] = (f16)b.y; r[6] = (f16)b.z; r[7] = (f16)b.w;
    return r;
}
__device__ __forceinline__ unsigned packh2(f16 a, f16 b) {
    union { f16 h[2]; unsigned u; } p;
    p.h[0] = a; p.h[1] = b;
    return p.u;
}

// swizzle n f32 weights (o-major, K inner) into MFMA B-frag f16 layout in LDS
__device__ __forceinline__ void swz_load(const float* __restrict__ W, int K, int n,
                                         f16* dst, int tid, int nthr) {
    for (int p = tid; p < n; p += nthr) {
        int j = p & 7, ln = (p >> 3) & 63, nt = (p >> 9) & 3, ch = p >> 11;
        int k = ch * 32 + ((ln >> 4) << 3) + j;
        int o = nt * 16 + (ln & 15);
        dst[p] = (f16)W[o * K + k];
    }
}

// One block per batch: 1024 threads = 16 waves = 4 groups x 4 waves.
// Phases separated ONLY by __syncthreads (all barriers uniform across the block).
__global__ __launch_bounds__(1024, 4) void k_all(
    const float* __restrict__ feat, const int* __restrict__ types,
    const float* __restrict__ prev,
    const float* __restrict__ enc_w1, const float* __restrict__ enc_b1,
    const float* __restrict__ enc_w2, const float* __restrict__ enc_b2,
    const float* __restrict__ cont, const float* __restrict__ gnn_w,
    const float* __restrict__ gnn_b,
    const float* __restrict__ w_ih, const float* __restrict__ w_hh,
    const float* __restrict__ b_ih, const float* __restrict__ b_hh,
    const float* __restrict__ hw1, const float* __restrict__ hb1,
    const float* __restrict__ hw2, const float* __restrict__ hb2,
    f16* __restrict__ nrmp, float* __restrict__ sclp, int* __restrict__ idx,
    f16* __restrict__ M0, f16* __restrict__ M1,
    f16* __restrict__ h1p, f16* __restrict__ h2p,
    float* __restrict__ lat, float* __restrict__ state_out)
{
    __shared__ __align__(16) unsigned char smem[50176];
    int* cntl   = (int*)(smem + 49664);    // [10] persists all phases
    float* ctxl = (float*)(smem + 49728);  // [64] persists gnn1 -> head

    const int tid = threadIdx.x;
    const int w = tid >> 6, lane = tid & 63;
    const int g = w >> 2, wg = w & 3;          // group 0..3, wave-in-group 0..3
    const int l15 = lane & 15, quad = lane >> 4;
    const int b = blockIdx.x;

    if (tid < NTYPES) cntl[tid] = 0;
    __syncthreads();

    // ================= phase E: encoder + bucketing (16 tiles, 4/group) ======
    {
        f16* w2s  = (f16*)smem;                          // 8192 B
        f16* tw   = (f16*)(smem + 8192 + w * 2304);      // 16*72 f16 per wave
        float* fw = (float*)(smem + 45056 + w * 192);    // 48 f32 per wave
        int* pkb  = (int*)(smem + 48128 + g * 256);      // 64 int per group
        swz_load(enc_w2, 64, 4096, w2s, tid, 1024);
        float w10 = enc_w1[lane * 3], w11 = enc_w1[lane * 3 + 1],
              w12 = enc_w1[lane * 3 + 2], b1l = enc_b1[lane];
        float b2c[4];
#pragma unroll
        for (int nt = 0; nt < 4; ++nt) b2c[nt] = enc_b2[nt * 16 + l15];
        const f16x8* wbf = (const f16x8*)w2s;
        for (int it = 0; it < 4; ++it) {
            int tl = g * 4 + it;                  // tile within batch
            if (wg == 0) {
                int lr = tl * 64 + lane;          // row within batch
                int t = types[b * NN + lr];
                int pos = atomicAdd(&cntl[t], 1);
                int pk = (b * NTYPES + t) * CAP + pos;
                idx[pk] = lr;
                pkb[lane] = pk;
            }
            int rowbase = tl * 64 + wg * 16;
            if (lane < 48) fw[lane] = feat[((size_t)b * NN + rowbase) * 3 + lane];
            __syncthreads();   // pkb/fbuf (+w2s on it=0) ready
#pragma unroll
            for (int r = 0; r < 16; ++r) {
                float x0 = fw[r * 3], x1 = fw[r * 3 + 1], x2 = fw[r * 3 + 2];
                float hv = fmaxf(fmaf(w10, x0, fmaf(w11, x1, fmaf(w12, x2, b1l))), 0.f);
                tw[r * 72 + lane] = (f16)hv;
            }
            __builtin_amdgcn_sched_barrier(0);    // tw is wave-local
            f16x8 a0 = *(const f16x8*)&tw[l15 * 72 + quad * 8];
            f16x8 a1 = *(const f16x8*)&tw[l15 * 72 + 32 + quad * 8];
            f32x4 acc[4];
#pragma unroll
            for (int nt = 0; nt < 4; ++nt) {
                f32x4 c = {0.f, 0.f, 0.f, 0.f};
                c = MFMA16(a0, wbf[(0 * 4 + nt) * 64 + lane], c);
                c = MFMA16(a1, wbf[(1 * 4 + nt) * 64 + lane], c);
                acc[nt] = c;
            }
#pragma unroll
            for (int i = 0; i < 4; ++i) {
                float v[4]; float ss = 0.f;
#pragma unroll
                for (int nt = 0; nt < 4; ++nt) { v[nt] = acc[nt][i] + b2c[nt]; ss = fmaf(v[nt], v[nt], ss); }
                ss += __shfl_xor(ss, 1, 64); ss += __shfl_xor(ss, 2, 64);
                ss += __shfl_xor(ss, 4, 64); ss += __shfl_xor(ss, 8, 64);
                float nm = fmaxf(sqrtf(ss), 1e-12f);
                float rinv = 1.f / nm;
                int pk = pkb[wg * 16 + quad * 4 + i];
#pragma unroll
                for (int nt = 0; nt < 4; ++nt)
                    nrmp[(size_t)pk * 64 + nt * 16 + l15] = (f16)(v[nt] * rinv);
                if (l15 == 0) sclp[pk] = nm;
            }
            __syncthreads();   // pkb reuse next iteration
        }
    }

    const int gt = tid & 255;            // thread within group
    const int srr = gt & 15, sq4 = gt >> 4;   // staging row-pair / col-quad

    // ================= M build (used for M0 and M1), uniform barriers ========
    // 3 rounds x (uniform chunk count over the 4 concurrent buckets).
    #define BUILD_M(SRC_H, USE_SCALE, MDST)                                          \
    {                                                                                \
        f16* nT = (f16*)(smem + g * 10240);                                          \
        f16* hT = (f16*)(smem + g * 10240 + 5120);                                   \
        for (int r = 0; r < 3; ++r) {                                                \
            int tg = r * 4 + g;                                                      \
            bool valid = tg < NTYPES;                                                \
            int bt = b * NTYPES + (valid ? tg : 0);                                  \
            int c = valid ? cntl[tg] : 0;                                            \
            int cmax = 0;                                                            \
            for (int gg = 0; gg < 4; ++gg) {                                         \
                int tgg = r * 4 + gg;                                                \
                if (tgg < NTYPES) cmax = max(cmax, cntl[tgg]);                       \
            }                                                                        \
            int nch = (cmax + 31) >> 5;                                              \
            const f16* nb = nrmp + (size_t)bt * CAPE;                                \
            const f16* hb = SRC_H + (size_t)bt * CAPE;                               \
            const float* sb = sclp + (size_t)bt * CAP;                               \
            f32x4 acc[4] = {{0.f,0.f,0.f,0.f},{0.f,0.f,0.f,0.f},                     \
                            {0.f,0.f,0.f,0.f},{0.f,0.f,0.f,0.f}};                    \
            for (int ch = 0; ch < nch; ++ch) {                                       \
                __syncthreads();                                                     \
                f16x4 a[2], hh[2];                                                   \
                a[0] = (f16x4){0,0,0,0}; a[1] = a[0]; hh[0] = a[0]; hh[1] = a[0];    \
                for (int u = 0; u < 2; ++u) {                                        \
                    int mi = ch * 32 + 2 * srr + u;                                  \
                    if (mi < c) {                                                    \
                        a[u] = *(const f16x4*)&nb[(size_t)mi * 64 + 4 * sq4];        \
                        if (USE_SCALE) {                                             \
                            f16 sm = (f16)sb[mi];                                    \
                            hh[u] = a[u] * (f16x4){sm, sm, sm, sm};                  \
                        } else {                                                     \
                            hh[u] = *(const f16x4*)&hb[(size_t)mi * 64 + 4 * sq4];   \
                        }                                                            \
                    }                                                                \
                }                                                                    \
                for (int i = 0; i < 4; ++i) {                                        \
                    *(unsigned*)&nT[(4 * sq4 + i) * TSTR3 + 2 * srr] =               \
                        packh2(a[0][i], a[1][i]);                                    \
                    *(unsigned*)&hT[(4 * sq4 + i) * TSTR3 + 2 * srr] =               \
                        packh2(hh[0][i], hh[1][i]);                                  \
                }                                                                    \
                __syncthreads();                                                     \
                f16x8 af = *(const f16x8*)&nT[(wg * 16 + l15) * TSTR3 + quad * 8];   \
                for (int nt = 0; nt < 4; ++nt) {                                     \
                    f16x8 bfv = *(const f16x8*)&hT[(nt * 16 + l15) * TSTR3 + quad * 8];\
                    acc[nt] = MFMA16(af, bfv, acc[nt]);                              \
                }                                                                    \
            }                                                                        \
            if (valid) {                                                             \
                f16* Mo = (MDST) + (size_t)bt * 4096;                                \
                for (int nt = 0; nt < 4; ++nt)                                       \
                    for (int i = 0; i < 4; ++i)                                      \
                        Mo[(wg * 16 + quad * 4 + i) * 64 + nt * 16 + l15] =          \
                            (f16)acc[nt][i];                                         \
            }                                                                        \
        }                                                                            \
    }

    BUILD_M(nrmp, true, M0)     // M0 = nrm^T @ (scl*nrm)

    // ================= gnn layer 0 ===========================================
    {
        __syncthreads();                         // M-phase LDS reads done
        f16* gs = (f16*)smem;                    // 8192 B
        f16* dsg = (f16*)(smem + 8192 + g * 8192);
        swz_load(gnn_w, 64, 4096, gs, tid, 1024);
        __syncthreads();                         // gs ready
        const f16x8* gbf = (const f16x8*)gs;
        float gbl[4];
#pragma unroll
        for (int nt = 0; nt < 4; ++nt) gbl[nt] = gnn_b[nt * 16 + l15];
        for (int r = 0; r < 3; ++r) {
            int tg = r * 4 + g;
            bool valid = tg < NTYPES;
            int bt = b * NTYPES + (valid ? tg : 0);
            int c = valid ? cntl[tg] : 0;
            if (valid) {
                float sg_[NTYPES];
#pragma unroll
                for (int j = 0; j < NTYPES; ++j) sg_[j] = sigm(cont[tg * NTYPES + j]);
                float ca[16];
#pragma unroll
                for (int i = 0; i < 16; ++i) ca[i] = 0.f;
#pragma unroll
                for (int j = 0; j < NTYPES; ++j) {
                    const f16* Mr = M0 + ((size_t)b * NTYPES + j) * 4096 + (wg * 16 + l15) * 64;
                    f16x8 m0 = *(const f16x8*)&Mr[quad * 8];
                    f16x8 m1 = *(const f16x8*)&Mr[32 + quad * 8];
                    float sv = sg_[j];
#pragma unroll
                    for (int e = 0; e < 8; ++e) {
                        ca[e]     = fmaf(sv, (float)m0[e], ca[e]);
                        ca[8 + e] = fmaf(sv, (float)m1[e], ca[8 + e]);
                    }
                }
                f16x8 ca0, ca1;
#pragma unroll
                for (int i = 0; i < 8; ++i) { ca0[i] = (f16)ca[i]; ca1[i] = (f16)ca[8 + i]; }
#pragma unroll
                for (int nt = 0; nt < 4; ++nt) {
                    f32x4 dd = {0.f, 0.f, 0.f, 0.f};
                    dd = MFMA16(ca0, gbf[(0 * 4 + nt) * 64 + lane], dd);
                    dd = MFMA16(ca1, gbf[(1 * 4 + nt) * 64 + lane], dd);
#pragma unroll
                    for (int i = 0; i < 4; ++i) {
                        int d = wg * 16 + quad * 4 + i;
                        int pos = (((d >> 5) * 4 + nt) * 64 + ((d >> 3) & 3) * 16 + l15) * 8 + (d & 7);
                        dsg[pos] = (f16)dd[i];
                    }
                }
            }
            __syncthreads();   // D ready
            if (valid && c > 0) {
                const f16* nb = nrmp + (size_t)bt * CAPE;
                const float* sb = sclp + (size_t)bt * CAP;
                f16* hob = h1p + (size_t)bt * CAPE;
                const f16x8* dbf = (const f16x8*)dsg;
                for (int g2 = wg; g2 * 16 < c; g2 += 4) {
                    int tb2 = g2 * 16;
                    int rA = tb2 + l15; if (rA >= c) rA = c - 1;
                    const f16* na = nb + (size_t)rA * 64;
                    f16x8 a0 = *(const f16x8*)&na[quad * 8];
                    f16x8 a1 = *(const f16x8*)&na[32 + quad * 8];
                    f32x4 acc1[4], acc2[4];
#pragma unroll
                    for (int nt = 0; nt < 4; ++nt) {
                        f32x4 c1 = {0.f, 0.f, 0.f, 0.f}, c2 = {0.f, 0.f, 0.f, 0.f};
                        c1 = MFMA16(a0, dbf[(0 * 4 + nt) * 64 + lane], c1);
                        c1 = MFMA16(a1, dbf[(1 * 4 + nt) * 64 + lane], c1);
                        c2 = MFMA16(a0, gbf[(0 * 4 + nt) * 64 + lane], c2);
                        c2 = MFMA16(a1, gbf[(1 * 4 + nt) * 64 + lane], c2);
                        acc1[nt] = c1; acc2[nt] = c2;
                    }
#pragma unroll
                    for (int i = 0; i < 4; ++i) {
                        int rr = tb2 + quad * 4 + i;
                        if (rr < c) {
                            float sm = sb[rr];
#pragma unroll
                            for (int nt = 0; nt < 4; ++nt) {
                                float v = fmaxf(fmaf(sm, acc2[nt][i], acc1[nt][i]) + gbl[nt], 0.f);
                                hob[(size_t)rr * 64 + nt * 16 + l15] = (f16)v;
                            }
                        }
                    }
                }
            }
            __syncthreads();   // dsg free for next round
        }
    }

    BUILD_M(h1p, false, M1)     // M1 = nrm^T @ h1

    // ================= gnn layer 1 (+ ctx in LDS) ============================
    {
        __syncthreads();
        f16* gs = (f16*)smem;
        f16* dsg = (f16*)(smem + 8192 + g * 8192);
        swz_load(gnn_w + 4096, 64, 4096, gs, tid, 1024);
        if (tid < 64) ctxl[tid] = 0.f;
        __syncthreads();                         // gs + ctxl ready
        const f16x8* gbf = (const f16x8*)gs;
        float gbl[4];
#pragma unroll
        for (int nt = 0; nt < 4; ++nt) gbl[nt] = gnn_b[HID + nt * 16 + l15];
        for (int r = 0; r < 3; ++r) {
            int tg = r * 4 + g;
            bool valid = tg < NTYPES;
            int bt = b * NTYPES + (valid ? tg : 0);
            int c = valid ? cntl[tg] : 0;
            if (valid && c > 0) {
                float sg_[NTYPES];
#pragma unroll
                for (int j = 0; j < NTYPES; ++j) sg_[j] = sigm(cont[tg * NTYPES + j]);
                float ca[16];
#pragma unroll
                for (int i = 0; i < 16; ++i) ca[i] = 0.f;
#pragma unroll
                for (int j = 0; j < NTYPES; ++j) {
                    const f16* Mr = M1 + ((size_t)b * NTYPES + j) * 4096 + (wg * 16 + l15) * 64;
                    f16x8 m0 = *(const f16x8*)&Mr[quad * 8];
                    f16x8 m1 = *(const f16x8*)&Mr[32 + quad * 8];
                    float sv = sg_[j];
#pragma unroll
                    for (int e = 0; e < 8; ++e) {
                        ca[e]     = fmaf(sv, (float)m0[e], ca[e]);
                        ca[8 + e] = fmaf(sv, (float)m1[e], ca[8 + e]);
                    }
                }
                f16x8 ca0, ca1;
#pragma unroll
                for (int i = 0; i < 8; ++i) { ca0[i] = (f16)ca[i]; ca1[i] = (f16)ca[8 + i]; }
#pragma unroll
                for (int nt = 0; nt < 4; ++nt) {
                    f32x4 dd = {0.f, 0.f, 0.f, 0.f};
                    dd = MFMA16(ca0, gbf[(0 * 4 + nt) * 64 + lane], dd);
                    dd = MFMA16(ca1, gbf[(1 * 4 + nt) * 64 + lane], dd);
#pragma unroll
                    for (int i = 0; i < 4; ++i) {
                        int d = wg * 16 + quad * 4 + i;
                        int pos = (((d >> 5) * 4 + nt) * 64 + ((d >> 3) & 3) * 16 + l15) * 8 + (d & 7);
                        dsg[pos] = (f16)dd[i];
                    }
                }
            }
            __syncthreads();
            if (valid && c > 0) {
                const f16* nb = nrmp + (size_t)bt * CAPE;
                const f16* hb = h1p + (size_t)bt * CAPE;
                f16* hob = h2p + (size_t)bt * CAPE;
                const f16x8* dbf = (const f16x8*)dsg;
                float cacc[4] = {0.f, 0.f, 0.f, 0.f};
                for (int g2 = wg; g2 * 16 < c; g2 += 4) {
                    int tb2 = g2 * 16;
                    int rA = tb2 + l15; if (rA >= c) rA = c - 1;
                    const f16* na = nb + (size_t)rA * 64;
                    f16x8 a0 = *(const f16x8*)&na[quad * 8];
                    f16x8 a1 = *(const f16x8*)&na[32 + quad * 8];
                    const f16* ha = hb + (size_t)rA * 64;
                    f16x8 h0 = *(const f16x8*)&ha[quad * 8];
                    f16x8 h1v = *(const f16x8*)&ha[32 + quad * 8];
                    f32x4 acc[4];
#pragma unroll
                    for (int nt = 0; nt < 4; ++nt) {
                        f32x4 cc = {0.f, 0.f, 0.f, 0.f};
                        cc = MFMA16(a0, dbf[(0 * 4 + nt) * 64 + lane], cc);
                        cc = MFMA16(a1, dbf[(1 * 4 + nt) * 64 + lane], cc);
                        cc = MFMA16(h0, gbf[(0 * 4 + nt) * 64 + lane], cc);
                        cc = MFMA16(h1v, gbf[(1 * 4 + nt) * 64 + lane], cc);
                        acc[nt] = cc;
                    }
#pragma unroll
                    for (int i = 0; i < 4; ++i) {
                        int rr = tb2 + quad * 4 + i;
                        if (rr < c) {
#pragma unroll
                            for (int nt = 0; nt < 4; ++nt) {
                                float v = fmaxf(acc[nt][i] + gbl[nt], 0.f);
                                hob[(size_t)rr * 64 + nt * 16 + l15] = (f16)v;
                                cacc[nt] += v;
                            }
                        }
                    }
                }
#pragma unroll
                for (int nt = 0; nt < 4; ++nt) {
                    float sv = cacc[nt];
                    sv += __shfl_xor(sv, 16, 64);
                    sv += __shfl_xor(sv, 32, 64);
                    if (quad == 0) atomicAdd(&ctxl[nt * 16 + l15], sv);
                }
            }
            __syncthreads();
        }
    }

    // ================= head: GRU (once) + per-bucket MFMA + lat scatter ======
    {
        __syncthreads();
        f16* ws_   = (f16*)smem;                   // 12288 B
        float* st  = (float*)(smem + 12288);
        float* cs  = (float*)(smem + 12416);
        float* ps  = (float*)(smem + 12672);
        float* gis = (float*)(smem + 12800);
        float* ghs = (float*)(smem + 13184);
        swz_load(hw1, 96, 6144, ws_, tid, 1024);
        if (tid < HID) cs[tid] = ctxl[tid] * (1.f / NN);
        if (tid >= HID && tid < HID + STATE) ps[tid - HID] = prev[b * STATE + tid - HID];
        __syncthreads();
        if (tid < 96) {
            float gi = b_ih[tid];
#pragma unroll 8
            for (int k = 0; k < HID; ++k) gi = fmaf(w_ih[tid * HID + k], cs[k], gi);
            float gh = b_hh[tid];
#pragma unroll
            for (int k = 0; k < STATE; ++k) gh = fmaf(w_hh[tid * STATE + k], ps[k], gh);
            gis[tid] = gi; ghs[tid] = gh;
        }
        __syncthreads();
        if (tid < STATE) {
            float r_ = sigm(gis[tid] + ghs[tid]);
            float z = sigm(gis[32 + tid] + ghs[32 + tid]);
            float nn2 = tanhf(gis[64 + tid] + r_ * ghs[64 + tid]);
            float v = (1.f - z) * nn2 + z * ps[tid];
            st[tid] = v;
            state_out[b * STATE + tid] = v;
        }
        __syncthreads();
        float b1c[4], w2c[4];
#pragma unroll
        for (int nt = 0; nt < 4; ++nt) { b1c[nt] = hb1[nt * 16 + l15]; w2c[nt] = hw2[nt * 16 + l15]; }
        float b2v = hb2[0];
        const float4* sp = (const float4*)st;
        f16x8 a2 = cvt8(sp[quad * 2], sp[quad * 2 + 1]);
        const f16x8* bfp = (const f16x8*)ws_;
        for (int r = 0; r < 3; ++r) {
            int tg = r * 4 + g;
            if (tg >= NTYPES) continue;
            int bt = b * NTYPES + tg;
            int c = cntl[tg];
            if (c == 0) continue;
            const f16* hb = h2p + (size_t)bt * CAPE;
            const int* lst = idx + (size_t)bt * CAP;
            for (int g2 = wg; g2 * 16 < c; g2 += 4) {
                int tb2 = g2 * 16;
                int rA = tb2 + l15; if (rA >= c) rA = c - 1;
                const f16* ha = hb + (size_t)rA * 64;
                f16x8 a0 = *(const f16x8*)&ha[quad * 8];
                f16x8 a1 = *(const f16x8*)&ha[32 + quad * 8];
                f32x4 acc[4];
#pragma unroll
                for (int nt = 0; nt < 4; ++nt) {
                    f32x4 cc = {0.f, 0.f, 0.f, 0.f};
                    cc = MFMA16(a0, bfp[(0 * 4 + nt) * 64 + lane], cc);
                    cc = MFMA16(a1, bfp[(1 * 4 + nt) * 64 + lane], cc);
                    cc = MFMA16(a2, bfp[(2 * 4 + nt) * 64 + lane], cc);
                    acc[nt] = cc;
                }
#pragma unroll
                for (int i = 0; i < 4; ++i) {
                    float s = 0.f;
#pragma unroll
                    for (int nt = 0; nt < 4; ++nt) s = fmaf(fmaxf(acc[nt][i] + b1c[nt], 0.f), w2c[nt], s);
                    s += __shfl_xor(s, 1, 64); s += __shfl_xor(s, 2, 64);
                    s += __shfl_xor(s, 4, 64); s += __shfl_xor(s, 8, 64);
                    int rr = tb2 + quad * 4 + i;
                    if (l15 == 0 && rr < c) {
                        int m = lst[rr];
                        lat[b * NN + m] = s + b2v;
                    }
                }
            }
        }
    }
}

extern "C" void kernel_launch(void* const* d_in, const int* in_sizes, int n_in,
                              void* d_out, int out_size, void* d_ws, size_t ws_size,
                              hipStream_t stream) {
    const float* feat   = (const float*)d_in[0];
    const int*   types  = (const int*)d_in[1];
    const float* prev   = (const float*)d_in[2];
    const float* enc_w1 = (const float*)d_in[3];
    const float* enc_b1 = (const float*)d_in[4];
    const float* enc_w2 = (const float*)d_in[5];
    const float* enc_b2 = (const float*)d_in[6];
    const float* cont   = (const float*)d_in[7];
    const float* gnn_w  = (const float*)d_in[8];
    const float* gnn_b  = (const float*)d_in[9];
    const float* w_ih   = (const float*)d_in[10];
    const float* w_hh   = (const float*)d_in[11];
    const float* b_ih   = (const float*)d_in[12];
    const float* b_hh   = (const float*)d_in[13];
    const float* hw1    = (const float*)d_in[14];
    const float* hb1    = (const float*)d_in[15];
    const float* hw2    = (const float*)d_in[16];
    const float* hb2    = (const float*)d_in[17];
    float* out = (float*)d_out;

    float* ws   = (float*)d_ws;
    f16*   nrmp = (f16*)ws;                    // 10485760 f16
    f16*   h1p  = (f16*)(ws + 5242880);        // 10485760 f16
    f16*   h2p  = (f16*)(ws + 10485760);       // 10485760 f16
    float* sclp = ws + 15728640;               // 163840 f32
    int*   idx  = (int*)(ws + 15892480);       // 163840 i32
    f16*   M0   = (f16*)(ws + 16057344);       // 2621440 f16
    f16*   M1   = (f16*)(ws + 17368064);       // 2621440 f16

    k_all<<<BB, 1024, 0, stream>>>(feat, types, prev,
                                   enc_w1, enc_b1, enc_w2, enc_b2,
                                   cont, gnn_w, gnn_b,
                                   w_ih, w_hh, b_ih, b_hh,
                                   hw1, hb1, hw2, hb2,
                                   nrmp, sclp, idx, M0, M1, h1p, h2p,
                                   out, out + BB * NN);
}

// Round 6
// 165.266 us; speedup vs baseline: 2.1479x; 1.9211x over previous
//
#include <hip/hip_runtime.h>
#include <math.h>

#define BB 64
#define NN 1024
#define HID 64
#define STATE 32
#define NTYPES 10
#define CAP 256           // per-bucket row capacity (c ~ Binom(1024,0.1), 16-sigma safe)
#define CAPE (CAP * 64)   // f16 elems per packed bucket matrix

typedef _Float16 f16;
typedef f16 f16x8 __attribute__((ext_vector_type(8)));
typedef f16 f16x4 __attribute__((ext_vector_type(4)));
typedef float f32x4 __attribute__((ext_vector_type(4)));

#define MFMA16(a, b, c) __builtin_amdgcn_mfma_f32_16x16x32_f16(a, b, c, 0, 0, 0)

__device__ __forceinline__ float sigm(float x) { return 1.f / (1.f + expf(-x)); }

__device__ __forceinline__ f16x8 cvt8(float4 a, float4 b) {
    f16x8 r;
    r[0] = (f16)a.x; r[1] = (f16)a.y; r[2] = (f16)a.z; r[3] = (f16)a.w;
    r[4] = (f16)b.x; r[5] = (f16)b.y; r[6] = (f16)b.z; r[7] = (f16)b.w;
    return r;
}
__device__ __forceinline__ unsigned packh2(f16 a, f16 b) {
    union { f16 h[2]; unsigned u; } p;
    p.h[0] = a; p.h[1] = b;
    return p.u;
}

// ---------------- prep: one-time weight swizzle into MFMA B-frag layout
//                  (scattered reads happen ONCE here, not per consumer block)
//                  + zero cnt/ctx
__global__ __launch_bounds__(256) void k_prep(
    const float* __restrict__ w2, const float* __restrict__ gw,
    const float* __restrict__ hw1, f16* __restrict__ out,
    int* __restrict__ cnt, float* __restrict__ ctx)
{
    int p = blockIdx.x * 256 + threadIdx.x;
    if (p < 18432) {
        const float* W; int K, pl;
        if (p < 12288) { int seg = p >> 12; pl = p & 4095; W = (seg == 0) ? w2 : gw + (seg - 1) * 4096; K = 64; }
        else { W = hw1; K = 96; pl = p - 12288; }
        int j = pl & 7, lane = (pl >> 3) & 63, nt = (pl >> 9) & 3, ch = pl >> 11;
        int k = ch * 32 + ((lane >> 4) << 3) + j;
        int o = nt * 16 + (lane & 15);
        out[p] = (f16)W[o * K + k];
        return;
    }
    int q = p - 18432;
    if (q < BB * NTYPES) { cnt[q] = 0; return; }
    q -= BB * NTYPES;
    if (q < BB * HID) ctx[q] = 0.f;
}

// ---------------- encoder (MFMA) + bucketing; writes nrm/scl BUCKET-PACKED
__global__ __launch_bounds__(256) void k_encoder(
    const float* __restrict__ feat,
    const float* __restrict__ w1, const float* __restrict__ b1,
    const f16* __restrict__ w2f, const float* __restrict__ b2,
    const int* __restrict__ types, int* __restrict__ idx, int* __restrict__ cnt,
    f16* __restrict__ nrmp, float* __restrict__ sclp)
{
    __shared__ f16 w2s[4096];
    __shared__ f16 tmp[4][16 * 72];
    __shared__ float fbuf[4][48];
    __shared__ int pkbuf[64];
    int tid = threadIdx.x, wave = tid >> 6, lane = tid & 63;
    int l15 = lane & 15, quad = lane >> 4;
    if (tid < 64) {
        int row = blockIdx.x * 64 + tid;
        int b = row >> 10;
        int t = types[row];
        int bt = b * NTYPES + t;
        int pos = atomicAdd(&cnt[bt], 1);
        idx[bt * CAP + pos] = row & (NN - 1);
        pkbuf[tid] = bt * CAP + pos;
    }
    { const uint4* s = (const uint4*)w2f; uint4* d = (uint4*)w2s;
      for (int i = tid; i < 512; i += 256) d[i] = s[i]; }
    float w10 = w1[lane * 3], w11 = w1[lane * 3 + 1], w12 = w1[lane * 3 + 2], b1l = b1[lane];
    int tb = blockIdx.x * 64 + wave * 16;
    if (lane < 48) fbuf[wave][lane] = feat[tb * 3 + lane];
    __syncthreads();
    f16* tw = &tmp[wave][0];
#pragma unroll
    for (int r = 0; r < 16; ++r) {
        float x0 = fbuf[wave][r * 3], x1 = fbuf[wave][r * 3 + 1], x2 = fbuf[wave][r * 3 + 2];
        float hv = fmaxf(fmaf(w10, x0, fmaf(w11, x1, fmaf(w12, x2, b1l))), 0.f);
        tw[r * 72 + lane] = (f16)hv;
    }
    __builtin_amdgcn_sched_barrier(0);
    f16x8 a0 = *(const f16x8*)&tw[l15 * 72 + quad * 8];
    f16x8 a1 = *(const f16x8*)&tw[l15 * 72 + 32 + quad * 8];
    const f16x8* bf = (const f16x8*)w2s;
    f32x4 acc[4];
#pragma unroll
    for (int nt = 0; nt < 4; ++nt) {
        f32x4 c = {0.f, 0.f, 0.f, 0.f};
        c = MFMA16(a0, bf[(0 * 4 + nt) * 64 + lane], c);
        c = MFMA16(a1, bf[(1 * 4 + nt) * 64 + lane], c);
        acc[nt] = c;
    }
    float b2c[4];
#pragma unroll
    for (int nt = 0; nt < 4; ++nt) b2c[nt] = b2[nt * 16 + l15];
#pragma unroll
    for (int i = 0; i < 4; ++i) {
        float v[4]; float ss = 0.f;
#pragma unroll
        for (int nt = 0; nt < 4; ++nt) { v[nt] = acc[nt][i] + b2c[nt]; ss = fmaf(v[nt], v[nt], ss); }
        ss += __shfl_xor(ss, 1, 64); ss += __shfl_xor(ss, 2, 64);
        ss += __shfl_xor(ss, 4, 64); ss += __shfl_xor(ss, 8, 64);
        float nm = fmaxf(sqrtf(ss), 1e-12f);
        float rinv = 1.f / nm;
        int pk = pkbuf[wave * 16 + quad * 4 + i];
#pragma unroll
        for (int nt = 0; nt < 4; ++nt)
            nrmp[(size_t)pk * 64 + nt * 16 + l15] = (f16)(v[nt] * rinv);
        if (l15 == 0) sclp[pk] = nm;
    }
}

// ---------------- M0_j = nrm_j^T @ (scl*nrm)_j ; packed sequential reads
#define TSTR2 72
__global__ __launch_bounds__(256) void k_buildM0(
    const int* __restrict__ cnt, const f16* __restrict__ nrmp,
    const float* __restrict__ sclp, f16* __restrict__ M0)
{
    __shared__ f16 nT[64 * TSTR2];
    __shared__ f16 hT[64 * TSTR2];
    int i0 = blockIdx.x;
    int xcd = i0 & 7, kk = i0 >> 3;
    int b = xcd + 8 * (kk / NTYPES);
    int t = kk % NTYPES;
    int bt = b * NTYPES + t;
    int c = cnt[bt];
    int tid = threadIdx.x, wave = tid >> 6, lane = tid & 63;
    int l15 = lane & 15, quad = lane >> 4;
    int r = tid & 15, q4 = tid >> 4;
    const f16* nb = nrmp + (size_t)bt * CAPE;
    const float* sb = sclp + (size_t)bt * CAP;
    f32x4 acc[4] = {{0.f,0.f,0.f,0.f},{0.f,0.f,0.f,0.f},{0.f,0.f,0.f,0.f},{0.f,0.f,0.f,0.f}};
    for (int k0 = 0; k0 < c; k0 += 64) {
        __syncthreads();
        f16x4 a[4], g[4];
#pragma unroll
        for (int u = 0; u < 4; ++u) { a[u] = (f16x4){0,0,0,0}; g[u] = (f16x4){0,0,0,0}; }
#pragma unroll
        for (int u = 0; u < 4; ++u) {
            int mi = k0 + 4 * r + u;
            if (mi < c) {
                a[u] = *(const f16x4*)&nb[(size_t)mi * 64 + 4 * q4];
                f16 sm = (f16)sb[mi]; f16x4 sv = {sm, sm, sm, sm};
                g[u] = a[u] * sv;
            }
        }
#pragma unroll
        for (int i = 0; i < 4; ++i) {
            *(unsigned*)&nT[(4 * q4 + i) * TSTR2 + 4 * r]     = packh2(a[0][i], a[1][i]);
            *(unsigned*)&nT[(4 * q4 + i) * TSTR2 + 4 * r + 2] = packh2(a[2][i], a[3][i]);
            *(unsigned*)&hT[(4 * q4 + i) * TSTR2 + 4 * r]     = packh2(g[0][i], g[1][i]);
            *(unsigned*)&hT[(4 * q4 + i) * TSTR2 + 4 * r + 2] = packh2(g[2][i], g[3][i]);
        }
        __syncthreads();
        f16x8 af0 = *(const f16x8*)&nT[(wave * 16 + l15) * TSTR2 + quad * 8];
        f16x8 af1 = *(const f16x8*)&nT[(wave * 16 + l15) * TSTR2 + 32 + quad * 8];
#pragma unroll
        for (int nt = 0; nt < 4; ++nt) {
            f16x8 bf0 = *(const f16x8*)&hT[(nt * 16 + l15) * TSTR2 + quad * 8];
            f16x8 bf1 = *(const f16x8*)&hT[(nt * 16 + l15) * TSTR2 + 32 + quad * 8];
            acc[nt] = MFMA16(af0, bf0, acc[nt]);
            acc[nt] = MFMA16(af1, bf1, acc[nt]);
        }
    }
    f16* Mo = M0 + (size_t)bt * 4096;
#pragma unroll
    for (int nt = 0; nt < 4; ++nt)
#pragma unroll
        for (int i = 0; i < 4; ++i)
            Mo[(wave * 16 + quad * 4 + i) * 64 + nt * 16 + l15] = (f16)acc[nt][i];
}

// ---------------- GNN layer 0 + fused M1 build; packed streams
__global__ __launch_bounds__(256) void k_gnn0_fused(
    const int* __restrict__ cnt, const float* __restrict__ cont,
    const f16* __restrict__ M, const f16* __restrict__ nrmp,
    const float* __restrict__ sclp,
    const f16* __restrict__ gwf, const float* __restrict__ gb,
    f16* __restrict__ h1p, f16* __restrict__ Mout)
{
    __shared__ f16 ds_[4096];
    __shared__ f16 gs[4096];
    __shared__ __align__(16) f16 nT[64 * TSTR2];
    __shared__ __align__(16) f16 hT[64 * TSTR2];
    int i0 = blockIdx.x;
    int xcd = i0 & 7, kk = i0 >> 3;
    int b = xcd + 8 * (kk / NTYPES);
    int t = kk % NTYPES;
    int bt = b * NTYPES + t;
    int c = cnt[bt];
    int tid = threadIdx.x, wave = tid >> 6, lane = tid & 63;
    int l15 = lane & 15, quad = lane >> 4;
    { const uint4* s2 = (const uint4*)gwf; uint4* d2 = (uint4*)gs;
      for (int i = tid; i < 512; i += 256) d2[i] = s2[i]; }
    float sg[NTYPES];
#pragma unroll
    for (int j = 0; j < NTYPES; ++j) sg[j] = sigm(cont[t * NTYPES + j]);
    float ca[16];
#pragma unroll
    for (int i = 0; i < 16; ++i) ca[i] = 0.f;
    const f16* Mb = M + (size_t)b * NTYPES * 4096;
#pragma unroll
    for (int j = 0; j < NTYPES; ++j) {
        const f16* Mr = Mb + j * 4096 + (wave * 16 + l15) * 64;
        f16x8 m0 = *(const f16x8*)&Mr[quad * 8];
        f16x8 m1 = *(const f16x8*)&Mr[32 + quad * 8];
        float sv = sg[j];
#pragma unroll
        for (int e = 0; e < 8; ++e) {
            ca[e]     = fmaf(sv, (float)m0[e], ca[e]);
            ca[8 + e] = fmaf(sv, (float)m1[e], ca[8 + e]);
        }
    }
    f16x8 ca0, ca1;
#pragma unroll
    for (int i = 0; i < 8; ++i) { ca0[i] = (f16)ca[i]; ca1[i] = (f16)ca[8 + i]; }
    __syncthreads();   // gs ready
    const f16x8* gbf = (const f16x8*)gs;
#pragma unroll
    for (int nt = 0; nt < 4; ++nt) {
        f32x4 dd = {0.f, 0.f, 0.f, 0.f};
        dd = MFMA16(ca0, gbf[(0 * 4 + nt) * 64 + lane], dd);
        dd = MFMA16(ca1, gbf[(1 * 4 + nt) * 64 + lane], dd);
#pragma unroll
        for (int i = 0; i < 4; ++i) {
            int d = wave * 16 + quad * 4 + i;
            int pos = (((d >> 5) * 4 + nt) * 64 + ((d >> 3) & 3) * 16 + l15) * 8 + (d & 7);
            ds_[pos] = (f16)dd[i];
        }
    }
    __syncthreads();   // D ready
    float gbl[4];
#pragma unroll
    for (int nt = 0; nt < 4; ++nt) gbl[nt] = gb[nt * 16 + l15];
    const f16* nb = nrmp + (size_t)bt * CAPE;
    const float* sb = sclp + (size_t)bt * CAP;
    f16* hob = h1p + (size_t)bt * CAPE;
    const f16x8* dbf = (const f16x8*)ds_;
    f32x4 macc[4];
#pragma unroll
    for (int nt = 0; nt < 4; ++nt) macc[nt] = (f32x4){0.f, 0.f, 0.f, 0.f};
    int nchunk = (c + 63) >> 6;
    for (int ch = 0; ch < nchunk; ++ch) {
        int tb = ch * 64 + wave * 16;
        int rA = tb + l15;
        bool okA = rA < c;
        int rAc = okA ? rA : (c - 1);
        const f16* na = nb + (size_t)rAc * 64;
        f16x8 a0 = *(const f16x8*)&na[quad * 8];
        f16x8 a1 = *(const f16x8*)&na[32 + quad * 8];
        f32x4 acc1[4], acc2[4];
#pragma unroll
        for (int nt = 0; nt < 4; ++nt) {
            f32x4 c1 = {0.f, 0.f, 0.f, 0.f}, c2 = {0.f, 0.f, 0.f, 0.f};
            c1 = MFMA16(a0, dbf[(0 * 4 + nt) * 64 + lane], c1);
            c1 = MFMA16(a1, dbf[(1 * 4 + nt) * 64 + lane], c1);
            c2 = MFMA16(a0, gbf[(0 * 4 + nt) * 64 + lane], c2);
            c2 = MFMA16(a1, gbf[(1 * 4 + nt) * 64 + lane], c2);
            acc1[nt] = c1; acc2[nt] = c2;
        }
        f16x4 hv[4];
#pragma unroll
        for (int nt = 0; nt < 4; ++nt) hv[nt] = (f16x4){0, 0, 0, 0};
#pragma unroll
        for (int i = 0; i < 4; ++i) {
            int rr = tb + quad * 4 + i;
            if (rr < c) {
                float sm = sb[rr];
#pragma unroll
                for (int nt = 0; nt < 4; ++nt) {
                    float v = fmaxf(fmaf(sm, acc2[nt][i], acc1[nt][i]) + gbl[nt], 0.f);
                    f16 vh = (f16)v;
                    hob[(size_t)rr * 64 + nt * 16 + l15] = vh;
                    hv[nt][i] = vh;
                }
            }
        }
        f16x8 z8 = {0, 0, 0, 0, 0, 0, 0, 0};
        f16x8 s0 = okA ? a0 : z8;
        f16x8 s1 = okA ? a1 : z8;
#pragma unroll
        for (int j = 0; j < 8; ++j) {
            nT[(quad * 8 + j) * TSTR2 + wave * 16 + l15]      = s0[j];
            nT[(32 + quad * 8 + j) * TSTR2 + wave * 16 + l15] = s1[j];
        }
#pragma unroll
        for (int nt = 0; nt < 4; ++nt)
            *(f16x4*)&hT[(nt * 16 + l15) * TSTR2 + wave * 16 + quad * 4] = hv[nt];
        __syncthreads();
        f16x8 af0 = *(const f16x8*)&nT[(wave * 16 + l15) * TSTR2 + quad * 8];
        f16x8 af1 = *(const f16x8*)&nT[(wave * 16 + l15) * TSTR2 + 32 + quad * 8];
#pragma unroll
        for (int nt = 0; nt < 4; ++nt) {
            f16x8 bf0 = *(const f16x8*)&hT[(nt * 16 + l15) * TSTR2 + quad * 8];
            f16x8 bf1 = *(const f16x8*)&hT[(nt * 16 + l15) * TSTR2 + 32 + quad * 8];
            macc[nt] = MFMA16(af0, bf0, macc[nt]);
            macc[nt] = MFMA16(af1, bf1, macc[nt]);
        }
        __syncthreads();
    }
    f16* Mo = Mout + (size_t)bt * 4096;
#pragma unroll
    for (int nt = 0; nt < 4; ++nt)
#pragma unroll
        for (int i = 0; i < 4; ++i)
            Mo[(wave * 16 + quad * 4 + i) * 64 + nt * 16 + l15] = (f16)macc[nt][i];
}

// ---------------- GNN layer 1 (+ ctx colsum); packed streams
__global__ __launch_bounds__(256) void k_gnn1(
    const int* __restrict__ cnt, const float* __restrict__ cont,
    const f16* __restrict__ M, const f16* __restrict__ nrmp,
    const f16* __restrict__ h1p,
    const f16* __restrict__ gwf, const float* __restrict__ gb,
    f16* __restrict__ h2p, float* __restrict__ ctx)
{
    __shared__ f16 ds_[4096];
    __shared__ f16 gs[4096];
    int i0 = blockIdx.x;
    int xcd = i0 & 7, kk = i0 >> 3;
    int b = xcd + 8 * (kk / NTYPES);
    int t = kk % NTYPES;
    int bt = b * NTYPES + t;
    int c = cnt[bt];
    if (c == 0) return;
    int tid = threadIdx.x, wave = tid >> 6, lane = tid & 63;
    int l15 = lane & 15, quad = lane >> 4;
    { const uint4* s2 = (const uint4*)gwf; uint4* d2 = (uint4*)gs;
      for (int i = tid; i < 512; i += 256) d2[i] = s2[i]; }
    float sg[NTYPES];
#pragma unroll
    for (int j = 0; j < NTYPES; ++j) sg[j] = sigm(cont[t * NTYPES + j]);
    float ca[16];
#pragma unroll
    for (int i = 0; i < 16; ++i) ca[i] = 0.f;
    const f16* Mb = M + (size_t)b * NTYPES * 4096;
#pragma unroll
    for (int j = 0; j < NTYPES; ++j) {
        const f16* Mr = Mb + j * 4096 + (wave * 16 + l15) * 64;
        f16x8 m0 = *(const f16x8*)&Mr[quad * 8];
        f16x8 m1 = *(const f16x8*)&Mr[32 + quad * 8];
        float sv = sg[j];
#pragma unroll
        for (int e = 0; e < 8; ++e) {
            ca[e]     = fmaf(sv, (float)m0[e], ca[e]);
            ca[8 + e] = fmaf(sv, (float)m1[e], ca[8 + e]);
        }
    }
    f16x8 ca0, ca1;
#pragma unroll
    for (int i = 0; i < 8; ++i) { ca0[i] = (f16)ca[i]; ca1[i] = (f16)ca[8 + i]; }
    __syncthreads();   // gs ready
    const f16x8* gbf = (const f16x8*)gs;
#pragma unroll
    for (int nt = 0; nt < 4; ++nt) {
        f32x4 dd = {0.f, 0.f, 0.f, 0.f};
        dd = MFMA16(ca0, gbf[(0 * 4 + nt) * 64 + lane], dd);
        dd = MFMA16(ca1, gbf[(1 * 4 + nt) * 64 + lane], dd);
#pragma unroll
        for (int i = 0; i < 4; ++i) {
            int d = wave * 16 + quad * 4 + i;
            int pos = (((d >> 5) * 4 + nt) * 64 + ((d >> 3) & 3) * 16 + l15) * 8 + (d & 7);
            ds_[pos] = (f16)dd[i];
        }
    }
    __syncthreads();   // D ready
    float gbl[4];
#pragma unroll
    for (int nt = 0; nt < 4; ++nt) gbl[nt] = gb[nt * 16 + l15];
    const f16* nb = nrmp + (size_t)bt * CAPE;
    const f16* hb = h1p + (size_t)bt * CAPE;
    f16* hob = h2p + (size_t)bt * CAPE;
    const f16x8* dbf = (const f16x8*)ds_;
    float cacc[4] = {0.f, 0.f, 0.f, 0.f};
    for (int g = wave; g * 16 < c; g += 4) {
        int tb = g * 16;
        int rA = tb + l15; if (rA >= c) rA = c - 1;
        const f16* na = nb + (size_t)rA * 64;
        f16x8 a0 = *(const f16x8*)&na[quad * 8];
        f16x8 a1 = *(const f16x8*)&na[32 + quad * 8];
        const f16* ha = hb + (size_t)rA * 64;
        f16x8 h0 = *(const f16x8*)&ha[quad * 8];
        f16x8 h1 = *(const f16x8*)&ha[32 + quad * 8];
        f32x4 acc[4];
#pragma unroll
        for (int nt = 0; nt < 4; ++nt) {
            f32x4 cc = {0.f, 0.f, 0.f, 0.f};
            cc = MFMA16(a0, dbf[(0 * 4 + nt) * 64 + lane], cc);
            cc = MFMA16(a1, dbf[(1 * 4 + nt) * 64 + lane], cc);
            cc = MFMA16(h0, gbf[(0 * 4 + nt) * 64 + lane], cc);
            cc = MFMA16(h1, gbf[(1 * 4 + nt) * 64 + lane], cc);
            acc[nt] = cc;
        }
#pragma unroll
        for (int i = 0; i < 4; ++i) {
            int rr = tb + quad * 4 + i;
            if (rr < c) {
#pragma unroll
                for (int nt = 0; nt < 4; ++nt) {
                    float v = fmaxf(acc[nt][i] + gbl[nt], 0.f);
                    hob[(size_t)rr * 64 + nt * 16 + l15] = (f16)v;
                    cacc[nt] += v;
                }
            }
        }
    }
#pragma unroll
    for (int nt = 0; nt < 4; ++nt) {
        float sv = cacc[nt];
        sv += __shfl_xor(sv, 16, 64);
        sv += __shfl_xor(sv, 32, 64);
        if (quad == 0) atomicAdd(&ctx[b * HID + nt * 16 + l15], sv);
    }
}

// ---------------- head + fused GRU; bucket-mapped, packed reads, lat scatter
__global__ __launch_bounds__(256) void k_head(
    const f16* __restrict__ h2p, const int* __restrict__ idx,
    const int* __restrict__ cnt, const float* __restrict__ ctx_sum,
    const float* __restrict__ prev,
    const float* __restrict__ w_ih, const float* __restrict__ w_hh,
    const float* __restrict__ b_ih, const float* __restrict__ b_hh,
    const f16* __restrict__ hwf, const float* __restrict__ b1,
    const float* __restrict__ w2, const float* __restrict__ b2,
    float* __restrict__ lat, float* __restrict__ state_out)
{
    __shared__ f16 ws_[6144];
    __shared__ __align__(16) float st[STATE];
    __shared__ float cs[HID], ps[STATE], gis[96], ghs[96];
    int i0 = blockIdx.x;
    int xcd = i0 & 7, kk = i0 >> 3;
    int b = xcd + 8 * (kk / NTYPES);
    int t = kk % NTYPES;
    int bt = b * NTYPES + t;
    int c = cnt[bt];
    int tid = threadIdx.x, wave = tid >> 6, lane = tid & 63;
    int l15 = lane & 15, quad = lane >> 4;
    { const uint4* s = (const uint4*)hwf; uint4* d = (uint4*)ws_;
      for (int i = tid; i < 768; i += 256) d[i] = s[i]; }
    if (tid < HID) cs[tid] = ctx_sum[b * HID + tid] * (1.f / NN);
    if (tid >= HID && tid < HID + STATE) ps[tid - HID] = prev[b * STATE + tid - HID];
    __syncthreads();
    if (tid < 96) {
        float gi = b_ih[tid];
#pragma unroll 8
        for (int k = 0; k < HID; ++k) gi = fmaf(w_ih[tid * HID + k], cs[k], gi);
        float gh = b_hh[tid];
#pragma unroll
        for (int k = 0; k < STATE; ++k) gh = fmaf(w_hh[tid * STATE + k], ps[k], gh);
        gis[tid] = gi; ghs[tid] = gh;
    }
    __syncthreads();
    if (tid < STATE) {
        float r = sigm(gis[tid] + ghs[tid]);
        float z = sigm(gis[32 + tid] + ghs[32 + tid]);
        float nn = tanhf(gis[64 + tid] + r * ghs[64 + tid]);
        float v = (1.f - z) * nn + z * ps[tid];
        st[tid] = v;
        if (t == 0) state_out[b * STATE + tid] = v;   // one bucket per batch writes
    }
    __syncthreads();
    if (c == 0) return;
    float b1c[4], w2c[4];
#pragma unroll
    for (int nt = 0; nt < 4; ++nt) { b1c[nt] = b1[nt * 16 + l15]; w2c[nt] = w2[nt * 16 + l15]; }
    float b2v = b2[0];
    const float4* sp = (const float4*)st;
    f16x8 a2 = cvt8(sp[quad * 2], sp[quad * 2 + 1]);
    const f16x8* bf = (const f16x8*)ws_;
    const f16* hb = h2p + (size_t)bt * CAPE;
    const int* lst = idx + (size_t)bt * CAP;
    for (int g = wave; g * 16 < c; g += 4) {
        int tb = g * 16;
        int rA = tb + l15; if (rA >= c) rA = c - 1;
        const f16* ha = hb + (size_t)rA * 64;
        f16x8 a0 = *(const f16x8*)&ha[quad * 8];
        f16x8 a1 = *(const f16x8*)&ha[32 + quad * 8];
        f32x4 acc[4];
#pragma unroll
        for (int nt = 0; nt < 4; ++nt) {
            f32x4 cc = {0.f, 0.f, 0.f, 0.f};
            cc = MFMA16(a0, bf[(0 * 4 + nt) * 64 + lane], cc);
            cc = MFMA16(a1, bf[(1 * 4 + nt) * 64 + lane], cc);
            cc = MFMA16(a2, bf[(2 * 4 + nt) * 64 + lane], cc);
            acc[nt] = cc;
        }
#pragma unroll
        for (int i = 0; i < 4; ++i) {
            float s = 0.f;
#pragma unroll
            for (int nt = 0; nt < 4; ++nt) s = fmaf(fmaxf(acc[nt][i] + b1c[nt], 0.f), w2c[nt], s);
            s += __shfl_xor(s, 1, 64); s += __shfl_xor(s, 2, 64);
            s += __shfl_xor(s, 4, 64); s += __shfl_xor(s, 8, 64);
            int rr = tb + quad * 4 + i;
            if (l15 == 0 && rr < c) {
                int m = lst[rr];
                lat[b * NN + m] = s + b2v;
            }
        }
    }
}

extern "C" void kernel_launch(void* const* d_in, const int* in_sizes, int n_in,
                              void* d_out, int out_size, void* d_ws, size_t ws_size,
                              hipStream_t stream) {
    const float* feat   = (const float*)d_in[0];
    const int*   types  = (const int*)d_in[1];
    const float* prev   = (const float*)d_in[2];
    const float* enc_w1 = (const float*)d_in[3];
    const float* enc_b1 = (const float*)d_in[4];
    const float* enc_w2 = (const float*)d_in[5];
    const float* enc_b2 = (const float*)d_in[6];
    const float* cont   = (const float*)d_in[7];
    const float* gnn_w  = (const float*)d_in[8];
    const float* gnn_b  = (const float*)d_in[9];
    const float* w_ih   = (const float*)d_in[10];
    const float* w_hh   = (const float*)d_in[11];
    const float* b_ih   = (const float*)d_in[12];
    const float* b_hh   = (const float*)d_in[13];
    const float* hw1    = (const float*)d_in[14];
    const float* hb1    = (const float*)d_in[15];
    const float* hw2    = (const float*)d_in[16];
    const float* hb2    = (const float*)d_in[17];
    float* out = (float*)d_out;

    float* ws   = (float*)d_ws;
    f16*   nrmp = (f16*)ws;                    // 10485760 f16 (640*CAP*64)
    f16*   h1p  = (f16*)(ws + 5242880);        // 10485760 f16
    f16*   h2p  = (f16*)(ws + 10485760);       // 10485760 f16
    float* sclp = ws + 15728640;               // 163840 f32
    int*   idx  = (int*)(ws + 15892480);       // 163840 i32
    int*   cnt  = (int*)(ws + 16056320);       // 640 i32 (pad to 1024)
    f16*   M0   = (f16*)(ws + 16057344);       // 2621440 f16
    f16*   M1   = (f16*)(ws + 17368064);       // 2621440 f16
    float* ctx  = ws + 18678784;               // 4096 f32
    f16*   wfrag = (f16*)(ws + 18682880);      // 18432 f16
    f16*   w2f  = wfrag;
    f16*   gw0f = wfrag + 4096;
    f16*   gw1f = wfrag + 8192;
    f16*   hwf  = wfrag + 12288;

    k_prep<<<91, 256, 0, stream>>>(enc_w2, gnn_w, hw1, wfrag, cnt, ctx);
    k_encoder<<<BB * NN / 64, 256, 0, stream>>>(feat, enc_w1, enc_b1, w2f, enc_b2,
                                                types, idx, cnt, nrmp, sclp);
    k_buildM0<<<BB * NTYPES, 256, 0, stream>>>(cnt, nrmp, sclp, M0);
    k_gnn0_fused<<<BB * NTYPES, 256, 0, stream>>>(cnt, cont, M0, nrmp, sclp,
                                                  gw0f, gnn_b, h1p, M1);
    k_gnn1<<<BB * NTYPES, 256, 0, stream>>>(cnt, cont, M1, nrmp, h1p,
                                            gw1f, gnn_b + HID, h2p, ctx);
    k_head<<<BB * NTYPES, 256, 0, stream>>>(h2p, idx, cnt, ctx, prev,
                                            w_ih, w_hh, b_ih, b_hh,
                                            hwf, hb1, hw2, hb2, out, out + BB * NN);
}